// Round 11
// baseline (45.087 us; speedup 1.0000x reference)
//
#include <hip/hip_runtime.h>
#include <math.h>

#define NPATHS   1024
#define CANVAS_H 224
#define CANVAS_W 224
#define NPIX     (CANVAS_H * CANVAS_W)   // 50176
#define NSAMP    49          // linspace(0,1,50)[:-1] -> t_i = i/49
#define K2EXP    72.134752f  // 50/ln(2)
#define CULL_MARGIN 0.22f    // sigmoid(-11)~1.7e-5; absmax-validated rounds 6-7

#define CHUNKS   16
#define CPP      (NPATHS / CHUNKS)       // 64 paths per chunk

// Record (2x float4), coords pre-scaled by K2EXP:
//   rec0: [cx*K, cy*K, c2=-K*r, rr=(K*(r+margin))^2]
//   rec1: [cr*a, cg*a, cb*a, alpha]

__global__ __launch_bounds__(64) void path_setup_kernel(
    const float* __restrict__ cps,     // (P, 4, 4, 2)
    const float* __restrict__ colors,  // (P, 4)
    float* __restrict__ pd)            // (P, 8)
{
    const int tid = blockIdx.x * 64 + threadIdx.x;
    const int p = tid >> 2;
    const int s = tid & 3;

    const float4* cp4 = reinterpret_cast<const float4*>(cps);
    float4 a = cp4[p * 8 + s * 2];       // x0,y0,x1,y1
    float4 b = cp4[p * 8 + s * 2 + 1];   // x2,y2,x3,y3

    float sx = 0.0f, sy = 0.0f;
    for (int i = 0; i < NSAMP; ++i) {
        float t  = (float)i * (1.0f / 49.0f);
        float mt = 1.0f - t;
        float b0 = mt * mt * mt;
        float b1 = 3.0f * mt * mt * t;
        float b2 = 3.0f * mt * t * t;
        float b3 = t * t * t;
        sx += b0 * a.x + b1 * a.z + b2 * b.x + b3 * b.z;
        sy += b0 * a.y + b1 * a.w + b2 * b.y + b3 * b.w;
    }
    sx += __shfl_xor(sx, 1); sx += __shfl_xor(sx, 2);
    sy += __shfl_xor(sy, 1); sy += __shfl_xor(sy, 2);
    const float inv_n = 1.0f / 196.0f;
    float cx = sx * inv_n;
    float cy = sy * inv_n;

    float sr = 0.0f;
    for (int i = 0; i < NSAMP; ++i) {
        float t  = (float)i * (1.0f / 49.0f);
        float mt = 1.0f - t;
        float b0 = mt * mt * mt;
        float b1 = 3.0f * mt * mt * t;
        float b2 = 3.0f * mt * t * t;
        float b3 = t * t * t;
        float ptx = b0 * a.x + b1 * a.z + b2 * b.x + b3 * b.z;
        float pty = b0 * a.y + b1 * a.w + b2 * b.y + b3 * b.w;
        float dx = ptx - cx;
        float dy = pty - cy;
        sr += sqrtf(dx * dx + dy * dy);
    }
    sr += __shfl_xor(sr, 1); sr += __shfl_xor(sr, 2);
    float r = sr * inv_n;

    if (s == 0) {
        float4 col = reinterpret_cast<const float4*>(colors)[p];
        float rc = K2EXP * (r + CULL_MARGIN);
        float4* o = reinterpret_cast<float4*>(pd) + (size_t)p * 2;
        o[0] = make_float4(cx * K2EXP, cy * K2EXP, -K2EXP * r, rc * rc);
        o[1] = make_float4(col.x * col.w, col.y * col.w, col.z * col.w, col.w);
    }
}

// One WAVE = one (16x8 tile, 64-path chunk) pair; 2 px/lane (rows +0,+4).
// 128-thr blocks hold 2 chunks of the same tile (no barrier/LDS needed).
// Grid 3136 blocks -> 12.25 blocks/CU, ~6.1 waves/SIMD: fine-grained balance.
// Operands: VMEM broadcast loads of the 32 KB L1/L2-resident table.
// Whole-wave cull (scalar branch, no exec churn) skips the transcendental
// body for ~45% of (path, tile) pairs. Emits per-chunk affine map to cb.
__global__ __launch_bounds__(128) void render_kernel(
    const float* __restrict__ pd,   // (P, 8)
    float4* __restrict__ cb)        // (CHUNKS, NPIX)
{
    const int wave = __builtin_amdgcn_readfirstlane((int)(threadIdx.x >> 6));
    const int lane = threadIdx.x & 63;
    const int chunk = blockIdx.x * 2 + wave;
    const int lx = lane & 15;          // 0..15
    const int lq = lane >> 4;          // 0..3
    const int xx  = blockIdx.y * 16 + lx;    // 14 * 16 = 224
    const int yy0 = blockIdx.z * 8 + lq;     // 28 * 8  = 224
    const float pxs  = (float)xx * (K2EXP / 223.0f);
    const float py0s = (float)yy0 * (K2EXP / 223.0f);
    const float py1s = (float)(yy0 + 4) * (K2EXP / 223.0f);

    const float4* __restrict__ pdv =
        reinterpret_cast<const float4*>(pd) + (size_t)chunk * (CPP * 2);

    float T0 = 1.0f, Ar0 = 0.0f, Ag0 = 0.0f, Ab0 = 0.0f;
    float T1 = 1.0f, Ar1 = 0.0f, Ag1 = 0.0f, Ab1 = 0.0f;

#pragma unroll 2
    for (int p = 0; p < CPP; ++p) {
        float4 d0 = pdv[2 * p];        // cxs, cys, c2, rr
        float4 d1 = pdv[2 * p + 1];    // cr*a, cg*a, cb*a, alpha
        float dx  = pxs - d0.x;
        float dy0 = py0s - d0.y;
        float dy1 = py1s - d0.y;
        float dx2 = dx * dx;
        float d20 = __builtin_fmaf(dy0, dy0, dx2);
        float d21 = __builtin_fmaf(dy1, dy1, dx2);
        float dmin = fminf(d20, d21);
        if (__any(dmin < d0.w)) {
            float s0 = __builtin_amdgcn_sqrtf(d20);      // = K2EXP*dist0
            float s1 = __builtin_amdgcn_sqrtf(d21);
            float e0 = __builtin_amdgcn_exp2f(s0 + d0.z);
            float e1 = __builtin_amdgcn_exp2f(s1 + d0.z);
            float q0 = __builtin_amdgcn_rcpf(1.0f + e0); // sigmoid
            float q1 = __builtin_amdgcn_rcpf(1.0f + e1);
            float om0 = __builtin_fmaf(-d1.w, q0, 1.0f); // 1 - alpha*q
            float om1 = __builtin_fmaf(-d1.w, q1, 1.0f);
            T0 *= om0;
            T1 *= om1;
            Ar0 = __builtin_fmaf(Ar0, om0, d1.x * q0);
            Ag0 = __builtin_fmaf(Ag0, om0, d1.y * q0);
            Ab0 = __builtin_fmaf(Ab0, om0, d1.z * q0);
            Ar1 = __builtin_fmaf(Ar1, om1, d1.x * q1);
            Ag1 = __builtin_fmaf(Ag1, om1, d1.y * q1);
            Ab1 = __builtin_fmaf(Ab1, om1, d1.z * q1);
        }
    }

    const int pix0 = yy0 * CANVAS_W + xx;
    const int pix1 = (yy0 + 4) * CANVAS_W + xx;
    float4* row = cb + (size_t)chunk * NPIX;
    row[pix0] = make_float4(T0, Ar0, Ag0, Ab0);
    row[pix1] = make_float4(T1, Ar1, Ag1, Ab1);
}

__global__ __launch_bounds__(256) void combine_kernel(
    const float4* __restrict__ cb,     // (CHUNKS, NPIX)
    float* __restrict__ out)           // (3, H, W)
{
    int pix = blockIdx.x * 256 + threadIdx.x;   // 50176 = 196*256 exact
    float R = 1.0f, G = 1.0f, B = 1.0f;
#pragma unroll
    for (int k = 0; k < CHUNKS; ++k) {
        float4 w = cb[(size_t)k * NPIX + pix];
        R = __builtin_fmaf(R, w.x, w.y);
        G = __builtin_fmaf(G, w.x, w.z);
        B = __builtin_fmaf(B, w.x, w.w);
    }
    out[pix]            = R;
    out[NPIX + pix]     = G;
    out[2 * NPIX + pix] = B;
}

// Fallback if ws can't hold cb (needs 32KB + 12.85MB): single fused kernel
// (round-10 structure, adapted to the new record layout).
__global__ __launch_bounds__(1024) void render_direct_kernel(
    const float* __restrict__ pd,
    float* __restrict__ out)
{
    __shared__ float4 lds[NPATHS * 2];
    {
        const float4* src = reinterpret_cast<const float4*>(pd);
        lds[threadIdx.x]        = src[threadIdx.x];
        lds[threadIdx.x + 1024] = src[threadIdx.x + 1024];
    }
    __syncthreads();

    const int wave = __builtin_amdgcn_readfirstlane((int)(threadIdx.x >> 6));
    const int lane = threadIdx.x & 63;
    const int lx = lane & 15;
    const int lq = lane >> 4;
    const int xx  = blockIdx.x * 16 + lx;
    const int yy0 = blockIdx.y * 8 + lq;
    const float pxs  = (float)xx * (K2EXP / 223.0f);
    const float py0s = (float)yy0 * (K2EXP / 223.0f);
    const float py1s = (float)(yy0 + 4) * (K2EXP / 223.0f);

    const float4* plds = lds + wave * (CPP * 2);

    float T0 = 1.0f, Ar0 = 0.0f, Ag0 = 0.0f, Ab0 = 0.0f;
    float T1 = 1.0f, Ar1 = 0.0f, Ag1 = 0.0f, Ab1 = 0.0f;

#pragma unroll 4
    for (int p = 0; p < CPP; ++p) {
        float4 d0 = plds[2 * p];
        float4 d1 = plds[2 * p + 1];
        float dx  = pxs - d0.x;
        float dy0 = py0s - d0.y;
        float dy1 = py1s - d0.y;
        float dx2 = dx * dx;
        float d20 = __builtin_fmaf(dy0, dy0, dx2);
        float d21 = __builtin_fmaf(dy1, dy1, dx2);
        float s0 = __builtin_amdgcn_sqrtf(d20);
        float s1 = __builtin_amdgcn_sqrtf(d21);
        float e0 = __builtin_amdgcn_exp2f(s0 + d0.z);
        float e1 = __builtin_amdgcn_exp2f(s1 + d0.z);
        float q0 = __builtin_amdgcn_rcpf(1.0f + e0);
        float q1 = __builtin_amdgcn_rcpf(1.0f + e1);
        float om0 = __builtin_fmaf(-d1.w, q0, 1.0f);
        float om1 = __builtin_fmaf(-d1.w, q1, 1.0f);
        T0 *= om0; T1 *= om1;
        Ar0 = __builtin_fmaf(Ar0, om0, d1.x * q0);
        Ag0 = __builtin_fmaf(Ag0, om0, d1.y * q0);
        Ab0 = __builtin_fmaf(Ab0, om0, d1.z * q0);
        Ar1 = __builtin_fmaf(Ar1, om1, d1.x * q1);
        Ag1 = __builtin_fmaf(Ag1, om1, d1.y * q1);
        Ab1 = __builtin_fmaf(Ab1, om1, d1.z * q1);
    }

    __syncthreads();
    lds[wave * 128 + lane]      = make_float4(T0, Ar0, Ag0, Ab0);
    lds[wave * 128 + 64 + lane] = make_float4(T1, Ar1, Ag1, Ab1);
    __syncthreads();

    if (wave == 0) {
#pragma unroll
        for (int sub = 0; sub < 2; ++sub) {
            float R = 1.0f, G = 1.0f, Bb = 1.0f;
#pragma unroll
            for (int w = 0; w < 16; ++w) {
                float4 c = lds[w * 128 + sub * 64 + lane];
                R  = __builtin_fmaf(R,  c.x, c.y);
                G  = __builtin_fmaf(G,  c.x, c.z);
                Bb = __builtin_fmaf(Bb, c.x, c.w);
            }
            const int pix = (yy0 + sub * 4) * CANVAS_W + xx;
            out[pix]            = R;
            out[NPIX + pix]     = G;
            out[2 * NPIX + pix] = Bb;
        }
    }
}

extern "C" void kernel_launch(void* const* d_in, const int* in_sizes, int n_in,
                              void* d_out, int out_size, void* d_ws, size_t ws_size,
                              hipStream_t stream) {
    const float* cps    = (const float*)d_in[0];
    const float* colors = (const float*)d_in[1];
    float* out = (float*)d_out;
    float* pd  = (float*)d_ws;   // 32 KB

    path_setup_kernel<<<(NPATHS * 4) / 64, 64, 0, stream>>>(cps, colors, pd);

    const size_t PD_BYTES = (size_t)NPATHS * 8 * 4;
    const size_t CB_BYTES = (size_t)CHUNKS * NPIX * 16;
    if (ws_size >= PD_BYTES + CB_BYTES) {
        float4* cb = reinterpret_cast<float4*>((char*)d_ws + PD_BYTES);
        dim3 grid(CHUNKS / 2, CANVAS_W / 16, CANVAS_H / 8);  // 8 x 14 x 28
        render_kernel<<<grid, 128, 0, stream>>>(pd, cb);
        combine_kernel<<<NPIX / 256, 256, 0, stream>>>(cb, out);
    } else {
        dim3 grid(CANVAS_W / 16, CANVAS_H / 8);
        render_direct_kernel<<<grid, 1024, 0, stream>>>(pd, out);
    }
}

// Round 12
// 44.235 us; speedup vs baseline: 1.0193x; 1.0193x over previous
//
#include <hip/hip_runtime.h>
#include <math.h>

#define NPATHS   1024
#define CANVAS_H 224
#define CANVAS_W 224
#define NPIX     (CANVAS_H * CANVAS_W)   // 50176
#define NSAMP    49          // linspace(0,1,50)[:-1] -> t_i = i/49
#define K2EXP    72.134752f  // 50/ln(2)

#define CHUNKS   16
#define CPP      (NPATHS / CHUNKS)       // 64 paths per chunk

typedef __attribute__((ext_vector_type(2))) float f32x2;

// Record (2x float4), coords pre-scaled by K2EXP:
//   rec0: [cx*K, cy*K, c2=-K*r, alpha]
//   rec1: [cr*a, cg*a, cb*a, pad]

__global__ __launch_bounds__(64) void path_setup_kernel(
    const float* __restrict__ cps,     // (P, 4, 4, 2)
    const float* __restrict__ colors,  // (P, 4)
    float* __restrict__ pd)            // (P, 8)
{
    const int tid = blockIdx.x * 64 + threadIdx.x;
    const int p = tid >> 2;
    const int s = tid & 3;

    const float4* cp4 = reinterpret_cast<const float4*>(cps);
    float4 a = cp4[p * 8 + s * 2];       // x0,y0,x1,y1
    float4 b = cp4[p * 8 + s * 2 + 1];   // x2,y2,x3,y3

    float sx = 0.0f, sy = 0.0f;
    for (int i = 0; i < NSAMP; ++i) {
        float t  = (float)i * (1.0f / 49.0f);
        float mt = 1.0f - t;
        float b0 = mt * mt * mt;
        float b1 = 3.0f * mt * mt * t;
        float b2 = 3.0f * mt * t * t;
        float b3 = t * t * t;
        sx += b0 * a.x + b1 * a.z + b2 * b.x + b3 * b.z;
        sy += b0 * a.y + b1 * a.w + b2 * b.y + b3 * b.w;
    }
    sx += __shfl_xor(sx, 1); sx += __shfl_xor(sx, 2);
    sy += __shfl_xor(sy, 1); sy += __shfl_xor(sy, 2);
    const float inv_n = 1.0f / 196.0f;
    float cx = sx * inv_n;
    float cy = sy * inv_n;

    float sr = 0.0f;
    for (int i = 0; i < NSAMP; ++i) {
        float t  = (float)i * (1.0f / 49.0f);
        float mt = 1.0f - t;
        float b0 = mt * mt * mt;
        float b1 = 3.0f * mt * mt * t;
        float b2 = 3.0f * mt * t * t;
        float b3 = t * t * t;
        float ptx = b0 * a.x + b1 * a.z + b2 * b.x + b3 * b.z;
        float pty = b0 * a.y + b1 * a.w + b2 * b.y + b3 * b.w;
        float dx = ptx - cx;
        float dy = pty - cy;
        sr += sqrtf(dx * dx + dy * dy);
    }
    sr += __shfl_xor(sr, 1); sr += __shfl_xor(sr, 2);
    float r = sr * inv_n;

    if (s == 0) {
        float4 col = reinterpret_cast<const float4*>(colors)[p];
        float4* o = reinterpret_cast<float4*>(pd) + (size_t)p * 2;
        o[0] = make_float4(cx * K2EXP, cy * K2EXP, -K2EXP * r, col.w);
        o[1] = make_float4(col.x * col.w, col.y * col.w, col.z * col.w, 0.0f);
    }
}

// One WAVE = one (16x8 tile, 64-path chunk); 2 px/lane (rows +0,+4), entire
// sigmoid/composite body packed as f32x2 over the two sub-pixels
// (v_pk_fma_f32 / v_pk_mul_f32 -> ~13 VALU slots + 6 trans per path-iter).
// Straight-line, no cull, no exec churn. 3136 blocks x 2 waves = 12.25
// blocks/CU for fine-grained balance; operands via L1-resident VMEM broadcast.
__global__ __launch_bounds__(128) void render_kernel(
    const float* __restrict__ pd,   // (P, 8)
    float4* __restrict__ cb)        // (CHUNKS, NPIX)
{
    const int wave = __builtin_amdgcn_readfirstlane((int)(threadIdx.x >> 6));
    const int lane = threadIdx.x & 63;
    const int chunk = blockIdx.x * 2 + wave;
    const int lx = lane & 15;          // 0..15
    const int lq = lane >> 4;          // 0..3
    const int xx  = blockIdx.y * 16 + lx;    // 14 * 16 = 224
    const int yy0 = blockIdx.z * 8 + lq;     // 28 * 8  = 224
    const float pxs = (float)xx * (K2EXP / 223.0f);
    f32x2 pys;                                  // both sub-pixel y coords
    pys.x = (float)yy0 * (K2EXP / 223.0f);
    pys.y = (float)(yy0 + 4) * (K2EXP / 223.0f);

    const float4* __restrict__ pdv =
        reinterpret_cast<const float4*>(pd) + (size_t)chunk * (CPP * 2);

    f32x2 T  = {1.0f, 1.0f};
    f32x2 Ar = {0.0f, 0.0f};
    f32x2 Ag = {0.0f, 0.0f};
    f32x2 Ab = {0.0f, 0.0f};

#pragma unroll 4
    for (int p = 0; p < CPP; ++p) {
        float4 d0 = pdv[2 * p];        // cxs, cys, c2, alpha
        float4 d1 = pdv[2 * p + 1];    // cr*a, cg*a, cb*a, pad
        float dx  = pxs - d0.x;
        float dx2 = dx * dx;
        f32x2 cy2 = {d0.y, d0.y};
        f32x2 dy  = pys - cy2;                      // v_pk_add
        f32x2 dx2v = {dx2, dx2};
        f32x2 d2  = dy * dy + dx2v;                 // v_pk_fma
        float s0 = __builtin_amdgcn_sqrtf(d2.x);    // = K*dist
        float s1 = __builtin_amdgcn_sqrtf(d2.y);
        float e0 = __builtin_amdgcn_exp2f(s0 + d0.z);
        float e1 = __builtin_amdgcn_exp2f(s1 + d0.z);
        float q0 = __builtin_amdgcn_rcpf(1.0f + e0);
        float q1 = __builtin_amdgcn_rcpf(1.0f + e1);
        f32x2 q  = {q0, q1};
        f32x2 na = {-d0.w, -d0.w};
        f32x2 one = {1.0f, 1.0f};
        f32x2 om = na * q + one;                    // 1 - alpha*q  (v_pk_fma)
        T = T * om;                                 // v_pk_mul
        f32x2 crv = {d1.x, d1.x};
        f32x2 cgv = {d1.y, d1.y};
        f32x2 cbv = {d1.z, d1.z};
        Ar = Ar * om + crv * q;                     // 2x v_pk (mul+fma)
        Ag = Ag * om + cgv * q;
        Ab = Ab * om + cbv * q;
    }

    const int pix0 = yy0 * CANVAS_W + xx;
    const int pix1 = (yy0 + 4) * CANVAS_W + xx;
    float4* row = cb + (size_t)chunk * NPIX;
    row[pix0] = make_float4(T.x, Ar.x, Ag.x, Ab.x);
    row[pix1] = make_float4(T.y, Ar.y, Ag.y, Ab.y);
}

__global__ __launch_bounds__(256) void combine_kernel(
    const float4* __restrict__ cb,     // (CHUNKS, NPIX)
    float* __restrict__ out)           // (3, H, W)
{
    int pix = blockIdx.x * 256 + threadIdx.x;   // 50176 = 196*256 exact
    float R = 1.0f, G = 1.0f, B = 1.0f;
#pragma unroll
    for (int k = 0; k < CHUNKS; ++k) {
        float4 w = cb[(size_t)k * NPIX + pix];
        R = __builtin_fmaf(R, w.x, w.y);
        G = __builtin_fmaf(G, w.x, w.z);
        B = __builtin_fmaf(B, w.x, w.w);
    }
    out[pix]            = R;
    out[NPIX + pix]     = G;
    out[2 * NPIX + pix] = B;
}

// Fallback (ws too small): fused 16-wave LDS version (R10 structure).
__global__ __launch_bounds__(1024) void render_direct_kernel(
    const float* __restrict__ pd,
    float* __restrict__ out)
{
    __shared__ float4 lds[NPATHS * 2];
    {
        const float4* src = reinterpret_cast<const float4*>(pd);
        lds[threadIdx.x]        = src[threadIdx.x];
        lds[threadIdx.x + 1024] = src[threadIdx.x + 1024];
    }
    __syncthreads();

    const int wave = __builtin_amdgcn_readfirstlane((int)(threadIdx.x >> 6));
    const int lane = threadIdx.x & 63;
    const int lx = lane & 15;
    const int lq = lane >> 4;
    const int xx  = blockIdx.x * 16 + lx;
    const int yy0 = blockIdx.y * 8 + lq;
    const float pxs = (float)xx * (K2EXP / 223.0f);
    const float py0s = (float)yy0 * (K2EXP / 223.0f);
    const float py1s = (float)(yy0 + 4) * (K2EXP / 223.0f);

    const float4* plds = lds + wave * (CPP * 2);

    float T0 = 1.0f, Ar0 = 0.0f, Ag0 = 0.0f, Ab0 = 0.0f;
    float T1 = 1.0f, Ar1 = 0.0f, Ag1 = 0.0f, Ab1 = 0.0f;

#pragma unroll 4
    for (int p = 0; p < CPP; ++p) {
        float4 d0 = plds[2 * p];
        float4 d1 = plds[2 * p + 1];
        float dx  = pxs - d0.x;
        float dy0 = py0s - d0.y;
        float dy1 = py1s - d0.y;
        float dx2 = dx * dx;
        float d20 = __builtin_fmaf(dy0, dy0, dx2);
        float d21 = __builtin_fmaf(dy1, dy1, dx2);
        float s0 = __builtin_amdgcn_sqrtf(d20);
        float s1 = __builtin_amdgcn_sqrtf(d21);
        float e0 = __builtin_amdgcn_exp2f(s0 + d0.z);
        float e1 = __builtin_amdgcn_exp2f(s1 + d0.z);
        float q0 = __builtin_amdgcn_rcpf(1.0f + e0);
        float q1 = __builtin_amdgcn_rcpf(1.0f + e1);
        float om0 = __builtin_fmaf(-d0.w, q0, 1.0f);
        float om1 = __builtin_fmaf(-d0.w, q1, 1.0f);
        T0 *= om0; T1 *= om1;
        Ar0 = __builtin_fmaf(Ar0, om0, d1.x * q0);
        Ag0 = __builtin_fmaf(Ag0, om0, d1.y * q0);
        Ab0 = __builtin_fmaf(Ab0, om0, d1.z * q0);
        Ar1 = __builtin_fmaf(Ar1, om1, d1.x * q1);
        Ag1 = __builtin_fmaf(Ag1, om1, d1.y * q1);
        Ab1 = __builtin_fmaf(Ab1, om1, d1.z * q1);
    }

    __syncthreads();
    lds[wave * 128 + lane]      = make_float4(T0, Ar0, Ag0, Ab0);
    lds[wave * 128 + 64 + lane] = make_float4(T1, Ar1, Ag1, Ab1);
    __syncthreads();

    if (wave == 0) {
#pragma unroll
        for (int sub = 0; sub < 2; ++sub) {
            float R = 1.0f, G = 1.0f, Bb = 1.0f;
#pragma unroll
            for (int w = 0; w < 16; ++w) {
                float4 c = lds[w * 128 + sub * 64 + lane];
                R  = __builtin_fmaf(R,  c.x, c.y);
                G  = __builtin_fmaf(G,  c.x, c.z);
                Bb = __builtin_fmaf(Bb, c.x, c.w);
            }
            const int pix = (yy0 + sub * 4) * CANVAS_W + xx;
            out[pix]            = R;
            out[NPIX + pix]     = G;
            out[2 * NPIX + pix] = Bb;
        }
    }
}

extern "C" void kernel_launch(void* const* d_in, const int* in_sizes, int n_in,
                              void* d_out, int out_size, void* d_ws, size_t ws_size,
                              hipStream_t stream) {
    const float* cps    = (const float*)d_in[0];
    const float* colors = (const float*)d_in[1];
    float* out = (float*)d_out;
    float* pd  = (float*)d_ws;   // 32 KB

    path_setup_kernel<<<(NPATHS * 4) / 64, 64, 0, stream>>>(cps, colors, pd);

    const size_t PD_BYTES = (size_t)NPATHS * 8 * 4;
    const size_t CB_BYTES = (size_t)CHUNKS * NPIX * 16;
    if (ws_size >= PD_BYTES + CB_BYTES) {
        float4* cb = reinterpret_cast<float4*>((char*)d_ws + PD_BYTES);
        dim3 grid(CHUNKS / 2, CANVAS_W / 16, CANVAS_H / 8);  // 8 x 14 x 28
        render_kernel<<<grid, 128, 0, stream>>>(pd, cb);
        combine_kernel<<<NPIX / 256, 256, 0, stream>>>(cb, out);
    } else {
        dim3 grid(CANVAS_W / 16, CANVAS_H / 8);
        render_direct_kernel<<<grid, 1024, 0, stream>>>(pd, out);
    }
}